// Round 5
// baseline (132.309 us; speedup 1.0000x reference)
//
#include <hip/hip_runtime.h>

#define DD 128
#define NN 512
#define NODES 1024

typedef short bf16x8 __attribute__((ext_vector_type(8)));
typedef float f32x4 __attribute__((ext_vector_type(4)));

__device__ __forceinline__ float sigmoidf_(float x) {
  return __builtin_amdgcn_rcpf(1.f + __expf(-x));
}
__device__ __forceinline__ float siluf_(float x) { return x * sigmoidf_(x); }

__device__ __forceinline__ unsigned short f2bf_(float v) {
  unsigned int u = __float_as_uint(v);
  u += 0x7fffu + ((u >> 16) & 1u);   // RNE
  return (unsigned short)(u >> 16);
}
__device__ __forceinline__ unsigned cvtpk_(float lo, float hi) {
  unsigned r;
  asm("v_cvt_pk_bf16_f32 %0, %1, %2" : "=v"(r) : "v"(lo), "v"(hi));
  return r;
}
__device__ __forceinline__ float bflo_(unsigned u) { return __uint_as_float(u << 16); }
__device__ __forceinline__ float bfhi_(unsigned u) { return __uint_as_float(u & 0xffff0000u); }

// ---------------- prep kernel ----------------
__global__ __launch_bounds__(128) void prep_kernel(
    const float* __restrict__ sf, const float* __restrict__ cons,
    const float* __restrict__ eW1, const float* __restrict__ eb1,
    const float* __restrict__ eW2, const float* __restrict__ eb2,
    const float* __restrict__ vW1, const float* __restrict__ vb1,
    float* __restrict__ Ag, float* __restrict__ Bvg,
    unsigned short* __restrict__ E2V1T, float* __restrict__ m2,
    float* __restrict__ c1, float* __restrict__ mb)
{
  const int bid = blockIdx.x;
  const int d = threadIdx.x;
  if (bid < NODES) {
    float c = cons[bid];
    float aacc = c * eW1[258*DD + d];
    float bacc = eb1[d] + c * eW1[257*DD + d];
    const float* sfrow = sf + bid*DD;
    #pragma unroll 4
    for (int k = 0; k < DD; ++k) {
      float s = sfrow[k];
      aacc = fmaf(s, eW1[(128+k)*DD + d], aacc);
      bacc = fmaf(s, eW1[k*DD + d], bacc);
    }
    Ag[bid*DD + d]  = aacc;
    Bvg[bid*DD + d] = bacc;
  } else if (bid < NODES + 128) {
    // E2V1T[d][k^swz] = sum_t eW2[k,t]*vW1[t,d]  (bf16, pre-swizzled for B-frag reads)
    const int k = bid - NODES;
    float acc = 0.f;
    #pragma unroll 4
    for (int t = 0; t < DD; ++t) acc = fmaf(eW2[k*DD + t], vW1[t*DD + d], acc);
    E2V1T[d*DD + (k ^ ((d & 7) << 3))] = f2bf_(acc);
    if (d == 0) {
      float s = 0.f;
      for (int t = 0; t < DD; ++t) s += eW2[k*DD + t];
      m2[k] = s * (1.0f/128.0f);
    }
  } else {
    float acc = vb1[d];
    #pragma unroll 4
    for (int k = 0; k < DD; ++k) acc = fmaf(eb2[k], vW1[k*DD + d], acc);
    c1[d] = acc;
    if (d == 0) {
      float s = 0.f;
      for (int k = 0; k < DD; ++k) s += eb2[k];
      mb[0] = s * (1.0f/128.0f);
    }
  }
}

// ---------------- main kernel: one block per (b,i); barrier-free tile loop ----------------
__global__ __launch_bounds__(256, 4) void edge_kernel(
    const float* __restrict__ sf, const float* __restrict__ vf,
    const float* __restrict__ pos, const float* __restrict__ pm,
    const float* __restrict__ eW1,
    const float* __restrict__ eW2, const float* __restrict__ eb2,
    const float* __restrict__ sW1, const float* __restrict__ sb1,
    const float* __restrict__ sW2, const float* __restrict__ sb2,
    const float* __restrict__ vW2g, const float* __restrict__ vb2g,
    const float* __restrict__ lnw, const float* __restrict__ lnb,
    const float* __restrict__ Ag, const float* __restrict__ Bvg,
    const unsigned short* __restrict__ E2V1Tg, const float* __restrict__ m2g,
    const float* __restrict__ c1g, const float* __restrict__ mbg,
    float* __restrict__ sout, float* __restrict__ vout, float* __restrict__ ewout)
{
  __shared__ __align__(16) unsigned short eTs[128*128];   // 32 KB, [col][k^((col&7)<<3)]
  __shared__ __align__(16) float BvL[DD], w256L[DD], w259L[DD], m2L[DD];
  __shared__ float redS[4], redVx[4], redVy[4], redVz[4], redA[2], redB[2];

  const int tid = threadIdx.x;
  const int ni  = blockIdx.x;
  const int nb  = ni & ~(NN - 1);

  const int l   = tid & 63, w = tid >> 6;
  const int l15 = l & 15,  lg = l >> 4;
  const int d   = tid & 127, sub = tid >> 7;
  const int d0base = lg*8;

  // stage E2V1 (pre-swizzled bf16) into LDS
  {
    const uint4* src = (const uint4*)E2V1Tg;
    uint4* dst = (uint4*)eTs;
    #pragma unroll
    for (int it = 0; it < 8; ++it) dst[tid + it*256] = src[tid + it*256];
  }
  if (tid < 128) {
    BvL[tid]   = Bvg[(size_t)ni*DD + tid];
    w256L[tid] = eW1[256*DD + tid];
    w259L[tid] = eW1[259*DD + tid];
    m2L[tid]   = m2g[tid];
  }
  const float pix = pos[ni*3+0], piy = pos[ni*3+1], piz = pos[ni*3+2];
  float c1r[8], vw2r[8];
  #pragma unroll
  for (int ct = 0; ct < 8; ++ct) {
    int col = ct*16 + l15;
    c1r[ct] = c1g[col]; vw2r[ct] = vW2g[col];
  }
  const float mbv = mbg[0], vb2v = vb2g[0];

  float Sreg[4][8];
  #pragma unroll
  for (int kk = 0; kk < 4; ++kk)
    #pragma unroll
    for (int m = 0; m < 8; ++m) Sreg[kk][m] = 0.f;
  float vmx = 0.f, vmy = 0.f, vmz = 0.f, swacc = 0.f;

  __syncthreads();

  for (int t = 0; t < 8; ++t) {
    const int row = t*64 + w*16 + l15;     // this lane's A-row
    float px = pos[(nb + row)*3 + 0];
    float py = pos[(nb + row)*3 + 1];
    float pz = pos[(nb + row)*3 + 2];
    float rx = pix - px, ry = piy - py, rz = piz - pz;
    float dist = fmaxf(sqrtf(rx*rx + ry*ry + rz*rz), 1e-8f);
    float inv = __builtin_amdgcn_rcpf(dist);
    float dirx = rx*inv, diry = ry*inv, dirz = rz*inv;
    float mj = pm[(size_t)ni*NN + row];

    // ---- A: h in MFMA A-frag layout -> named uint4 packs (SROA-safe) ----
    uint4 pk0, pk1, pk2, pk3;
    float dot = 0.f;
    const float* agrow = Ag + (size_t)(nb + row)*DD;

#define A_STEP(KK, PK) {                                                        \
    const int d0 = (KK)*32 + d0base;                                            \
    float4 a0 = *(const float4*)(agrow + d0), a1 = *(const float4*)(agrow + d0 + 4); \
    float4 b0 = *(const float4*)&BvL[d0],   b1 = *(const float4*)&BvL[d0+4];    \
    float4 wa0= *(const float4*)&w256L[d0], wa1= *(const float4*)&w256L[d0+4];  \
    float4 wb0= *(const float4*)&w259L[d0], wb1= *(const float4*)&w259L[d0+4];  \
    float4 m20= *(const float4*)&m2L[d0],   m21= *(const float4*)&m2L[d0+4];    \
    float h0 = siluf_(b0.x + a0.x + dist*wa0.x + mj*wb0.x);                     \
    float h1 = siluf_(b0.y + a0.y + dist*wa0.y + mj*wb0.y);                     \
    float h2 = siluf_(b0.z + a0.z + dist*wa0.z + mj*wb0.z);                     \
    float h3 = siluf_(b0.w + a0.w + dist*wa0.w + mj*wb0.w);                     \
    float h4 = siluf_(b1.x + a1.x + dist*wa1.x + mj*wb1.x);                     \
    float h5 = siluf_(b1.y + a1.y + dist*wa1.y + mj*wb1.y);                     \
    float h6 = siluf_(b1.z + a1.z + dist*wa1.z + mj*wb1.z);                     \
    float h7 = siluf_(b1.w + a1.w + dist*wa1.w + mj*wb1.w);                     \
    PK.x = cvtpk_(h0, h1); PK.y = cvtpk_(h2, h3);                               \
    PK.z = cvtpk_(h4, h5); PK.w = cvtpk_(h6, h7);                               \
    dot += h0*m20.x + h1*m20.y + h2*m20.z + h3*m20.w                            \
         + h4*m21.x + h5*m21.y + h6*m21.z + h7*m21.w; }

    A_STEP(0, pk0)
    A_STEP(1, pk1)
    A_STEP(2, pk2)
    A_STEP(3, pk3)
#undef A_STEP

    dot += __shfl_xor(dot, 16);
    dot += __shfl_xor(dot, 32);
    const float w_full = mj * sigmoidf_(dot + mbv);
    if (lg == 0) {
      ewout[(size_t)ni*NN + row] = w_full;
      swacc += w_full;
    }

#define S_STEP(KK, PK) {                                          \
    Sreg[KK][0] = fmaf(w_full, bflo_(PK.x), Sreg[KK][0]);         \
    Sreg[KK][1] = fmaf(w_full, bfhi_(PK.x), Sreg[KK][1]);         \
    Sreg[KK][2] = fmaf(w_full, bflo_(PK.y), Sreg[KK][2]);         \
    Sreg[KK][3] = fmaf(w_full, bfhi_(PK.y), Sreg[KK][3]);         \
    Sreg[KK][4] = fmaf(w_full, bflo_(PK.z), Sreg[KK][4]);         \
    Sreg[KK][5] = fmaf(w_full, bfhi_(PK.z), Sreg[KK][5]);         \
    Sreg[KK][6] = fmaf(w_full, bflo_(PK.w), Sreg[KK][6]);         \
    Sreg[KK][7] = fmaf(w_full, bfhi_(PK.w), Sreg[KK][7]); }

    S_STEP(0, pk0)
    S_STEP(1, pk1)
    S_STEP(2, pk2)
    S_STEP(3, pk3)
#undef S_STEP

    const bf16x8 af0 = __builtin_bit_cast(bf16x8, pk0);
    const bf16x8 af1 = __builtin_bit_cast(bf16x8, pk1);
    const bf16x8 af2 = __builtin_bit_cast(bf16x8, pk2);
    const bf16x8 af3 = __builtin_bit_cast(bf16x8, pk3);

    // ---- B: wave-local MFMA over all 128 cols; gate reduce in-wave ----
    float gp[4] = {0.f, 0.f, 0.f, 0.f};
    #pragma unroll
    for (int ct = 0; ct < 8; ++ct) {
      const int col = ct*16 + l15;
      const int swz = (col & 7) << 3;
      const unsigned short* ecol = &eTs[col*DD];
      bf16x8 bf0 = *(const bf16x8*)&ecol[(  0 + d0base) ^ swz];
      bf16x8 bf1 = *(const bf16x8*)&ecol[( 32 + d0base) ^ swz];
      bf16x8 bf2 = *(const bf16x8*)&ecol[( 64 + d0base) ^ swz];
      bf16x8 bf3 = *(const bf16x8*)&ecol[( 96 + d0base) ^ swz];
      f32x4 c = {0.f, 0.f, 0.f, 0.f};
      c = __builtin_amdgcn_mfma_f32_16x16x32_bf16(af0, bf0, c, 0, 0, 0);
      c = __builtin_amdgcn_mfma_f32_16x16x32_bf16(af1, bf1, c, 0, 0, 0);
      c = __builtin_amdgcn_mfma_f32_16x16x32_bf16(af2, bf2, c, 0, 0, 0);
      c = __builtin_amdgcn_mfma_f32_16x16x32_bf16(af3, bf3, c, 0, 0, 0);
      gp[0] += siluf_(c[0] + c1r[ct]) * vw2r[ct];
      gp[1] += siluf_(c[1] + c1r[ct]) * vw2r[ct];
      gp[2] += siluf_(c[2] + c1r[ct]) * vw2r[ct];
      gp[3] += siluf_(c[3] + c1r[ct]) * vw2r[ct];
    }
    #pragma unroll
    for (int r = 0; r < 4; ++r) {
      float v = gp[r];
      v += __shfl_xor(v, 1);
      v += __shfl_xor(v, 2);
      v += __shfl_xor(v, 4);
      v += __shfl_xor(v, 8);
      const int srow = lg*4 + r;            // C row within the 16-block
      float wrow = __shfl(w_full, srow);
      float g = (v + vb2v) * wrow;
      float dx = __shfl(dirx, srow);
      float dy = __shfl(diry, srow);
      float dz = __shfl(dirz, srow);
      if (l15 == 0) {
        vmx = fmaf(g, dx, vmx);
        vmy = fmaf(g, dy, vmy);
        vmz = fmaf(g, dz, vmz);
      }
    }
  }

  // -------- epilogue --------
  __syncthreads();                 // all eTs reads done before aliasing
  float* scr   = (float*)eTs;
  float* Spart = scr;              // [4][128]
  float* SL    = scr + 512;
  float* partA = scr + 640;
  float* msgL  = scr + 768;
  float* u1L   = scr + 896;
  float* xoL   = scr + 1024;

  #pragma unroll
  for (int kk = 0; kk < 4; ++kk)
    #pragma unroll
    for (int m = 0; m < 8; ++m) {
      float v = Sreg[kk][m];
      v += __shfl_xor(v, 1);
      v += __shfl_xor(v, 2);
      v += __shfl_xor(v, 4);
      v += __shfl_xor(v, 8);
      Sreg[kk][m] = v;
    }
  if (l15 == 0) {
    #pragma unroll
    for (int kk = 0; kk < 4; ++kk)
      #pragma unroll
      for (int m = 0; m < 8; ++m)
        Spart[w*128 + kk*32 + lg*8 + m] = Sreg[kk][m];
  }
  {
    float sw = swacc;
    #pragma unroll
    for (int off = 1; off < 64; off <<= 1) sw += __shfl_xor(sw, off);
    if (l == 0) redS[w] = sw;
  }
  {
    float vx = vmx, vy = vmy, vz = vmz;
    #pragma unroll
    for (int off = 1; off < 64; off <<= 1) {
      vx += __shfl_xor(vx, off);
      vy += __shfl_xor(vy, off);
      vz += __shfl_xor(vz, off);
    }
    if (l == 0) { redVx[w] = vx; redVy[w] = vy; redVz[w] = vz; }
  }
  __syncthreads();
  if (tid < 128) SL[tid] = Spart[tid] + Spart[128+tid] + Spart[256+tid] + Spart[384+tid];
  if (tid == 0) {
    vout[ni*3 + 0] = vf[ni*3 + 0] + redVx[0]+redVx[1]+redVx[2]+redVx[3];
    vout[ni*3 + 1] = vf[ni*3 + 1] + redVy[0]+redVy[1]+redVy[2]+redVy[3];
    vout[ni*3 + 2] = vf[ni*3 + 2] + redVz[0]+redVz[1]+redVz[2]+redVz[3];
  }
  __syncthreads();
  const float sumwv = redS[0] + redS[1] + redS[2] + redS[3];

  // message_scalar = S@eW2 + sumw*eb2
  float p = 0.f;
  { int k0 = sub*64;
    #pragma unroll 4
    for (int k = k0; k < k0 + 64; ++k) p = fmaf(SL[k], eW2[k*DD + d], p); }
  if (sub) partA[d] = p;
  __syncthreads();
  if (!sub) msgL[d] = p + partA[d] + sumwv * eb2[d];
  __syncthreads();

  // u1 = silu([x, msg] @ sW1 + sb1)
  float q = 0.f;
  if (!sub) {
    const float* xr = sf + (size_t)ni*DD;
    #pragma unroll 4
    for (int tt = 0; tt < 128; ++tt) q = fmaf(xr[tt], sW1[tt*DD + d], q);
  } else {
    #pragma unroll 4
    for (int tt = 0; tt < 128; ++tt) q = fmaf(msgL[tt], sW1[(128 + tt)*DD + d], q);
  }
  if (sub) partA[d] = q;
  __syncthreads();
  if (!sub) u1L[d] = siluf_(q + partA[d] + sb1[d]);
  __syncthreads();

  // upd = u1 @ sW2 + sb2; x = sf + upd
  float r2 = 0.f;
  { int t0 = sub*64;
    #pragma unroll 4
    for (int tt = t0; tt < t0 + 64; ++tt) r2 = fmaf(u1L[tt], sW2[tt*DD + d], r2); }
  if (sub) partA[d] = r2;
  __syncthreads();
  if (!sub) xoL[d] = sf[(size_t)ni*DD + d] + r2 + partA[d] + sb2[d];
  __syncthreads();

  // LayerNorm
  if (tid < 128) {
    float v = xoL[tid];
    float s1 = v, s2 = v*v;
    #pragma unroll
    for (int off = 1; off < 64; off <<= 1) { s1 += __shfl_xor(s1, off); s2 += __shfl_xor(s2, off); }
    if ((tid & 63) == 0) { redA[tid >> 6] = s1; redB[tid >> 6] = s2; }
  }
  __syncthreads();
  if (tid < 128) {
    float s1 = redA[0] + redA[1], s2 = redB[0] + redB[1];
    float mu = s1 * 0.0078125f;
    float var = s2 * 0.0078125f - mu*mu;
    sout[(size_t)ni*DD + tid] = (xoL[tid] - mu) * rsqrtf(var + 1e-5f) * lnw[tid] + lnb[tid];
  }
}

extern "C" void kernel_launch(void* const* d_in, const int* in_sizes, int n_in,
                              void* d_out, int out_size, void* d_ws, size_t ws_size,
                              hipStream_t stream) {
  const float* sf   = (const float*)d_in[0];
  const float* vf   = (const float*)d_in[1];
  const float* pos  = (const float*)d_in[2];
  const float* pm   = (const float*)d_in[3];
  const float* cons = (const float*)d_in[4];
  const float* eW1  = (const float*)d_in[5];
  const float* eb1  = (const float*)d_in[6];
  const float* eW2  = (const float*)d_in[7];
  const float* eb2  = (const float*)d_in[8];
  const float* sW1  = (const float*)d_in[9];
  const float* sb1  = (const float*)d_in[10];
  const float* sW2  = (const float*)d_in[11];
  const float* sb2  = (const float*)d_in[12];
  const float* vW1  = (const float*)d_in[13];
  const float* vb1  = (const float*)d_in[14];
  const float* vW2  = (const float*)d_in[15];
  const float* vb2  = (const float*)d_in[16];
  const float* lnw  = (const float*)d_in[17];
  const float* lnb  = (const float*)d_in[18];

  float* ws   = (float*)d_ws;
  float* Ag   = ws;                              // 1024*128 f32
  float* Bvg  = ws + 131072;                     // 1024*128 f32
  float* m2   = ws + 262144;                     // 128
  float* c1   = ws + 262272;                     // 128
  float* mb   = ws + 262400;                     // 1 (+pad)
  unsigned short* E2V1T = (unsigned short*)(ws + 262404); // 128*128 bf16, 16B-aligned

  float* sout  = (float*)d_out;      // [2,512,128]
  float* vout  = sout + 131072;      // [2,512,3]
  float* ewout = sout + 134144;      // [2,512,512]

  hipLaunchKernelGGL(prep_kernel, dim3(NODES + 129), dim3(128), 0, stream,
                     sf, cons, eW1, eb1, eW2, eb2, vW1, vb1,
                     Ag, Bvg, E2V1T, m2, c1, mb);
  hipLaunchKernelGGL(edge_kernel, dim3(NODES), dim3(256), 0, stream,
                     sf, vf, pos, pm, eW1, eW2, eb2, sW1, sb1, sW2, sb2,
                     vW2, vb2, lnw, lnb, Ag, Bvg, E2V1T, m2, c1, mb,
                     sout, vout, ewout);
}

// Round 6
// 103.540 us; speedup vs baseline: 1.2779x; 1.2779x over previous
//
#include <hip/hip_runtime.h>

#define DD 128
#define NN 512
#define NODES 1024

typedef short bf16x8 __attribute__((ext_vector_type(8)));
typedef float f32x4 __attribute__((ext_vector_type(4)));

__device__ __forceinline__ float sigmoidf_(float x) {
  return __builtin_amdgcn_rcpf(1.f + __expf(-x));
}
__device__ __forceinline__ float siluf_(float x) { return x * sigmoidf_(x); }

__device__ __forceinline__ unsigned short f2bf_(float v) {
  unsigned int u = __float_as_uint(v);
  u += 0x7fffu + ((u >> 16) & 1u);   // RNE
  return (unsigned short)(u >> 16);
}
__device__ __forceinline__ unsigned cvtpk_(float lo, float hi) {
  unsigned r;
  asm("v_cvt_pk_bf16_f32 %0, %1, %2" : "=v"(r) : "v"(lo), "v"(hi));
  return r;
}
__device__ __forceinline__ float bflo_(unsigned u) { return __uint_as_float(u << 16); }
__device__ __forceinline__ float bfhi_(unsigned u) { return __uint_as_float(u & 0xffff0000u); }

// ---------------- prep kernel ----------------
__global__ __launch_bounds__(128) void prep_kernel(
    const float* __restrict__ sf, const float* __restrict__ cons,
    const float* __restrict__ eW1, const float* __restrict__ eb1,
    const float* __restrict__ eW2, const float* __restrict__ eb2,
    const float* __restrict__ vW1, const float* __restrict__ vb1,
    float* __restrict__ Ag, float* __restrict__ Bvg,
    unsigned short* __restrict__ E2V1T, float* __restrict__ m2,
    float* __restrict__ c1, float* __restrict__ mb)
{
  const int bid = blockIdx.x;
  const int d = threadIdx.x;
  if (bid < NODES) {
    float c = cons[bid];
    float aacc = c * eW1[258*DD + d];
    float bacc = eb1[d] + c * eW1[257*DD + d];
    const float* sfrow = sf + bid*DD;
    #pragma unroll 4
    for (int k = 0; k < DD; ++k) {
      float s = sfrow[k];
      aacc = fmaf(s, eW1[(128+k)*DD + d], aacc);
      bacc = fmaf(s, eW1[k*DD + d], bacc);
    }
    Ag[bid*DD + d]  = aacc;
    Bvg[bid*DD + d] = bacc;
  } else if (bid < NODES + 128) {
    // E2V1T[d][k^swz] = sum_t eW2[k,t]*vW1[t,d]  (bf16, pre-swizzled for B-frag reads)
    const int k = bid - NODES;
    float acc = 0.f;
    #pragma unroll 4
    for (int t = 0; t < DD; ++t) acc = fmaf(eW2[k*DD + t], vW1[t*DD + d], acc);
    E2V1T[d*DD + (k ^ ((d & 7) << 3))] = f2bf_(acc);
    if (d == 0) {
      float s = 0.f;
      for (int t = 0; t < DD; ++t) s += eW2[k*DD + t];
      m2[k] = s * (1.0f/128.0f);
    }
  } else {
    float acc = vb1[d];
    #pragma unroll 4
    for (int k = 0; k < DD; ++k) acc = fmaf(eb2[k], vW1[k*DD + d], acc);
    c1[d] = acc;
    if (d == 0) {
      float s = 0.f;
      for (int k = 0; k < DD; ++k) s += eb2[k];
      mb[0] = s * (1.0f/128.0f);
    }
  }
}

// ---------------- main kernel: one block per (b,i); barrier-free tile loop ----------------
__global__ __launch_bounds__(256, 2) void edge_kernel(
    const float* __restrict__ sf, const float* __restrict__ vf,
    const float* __restrict__ pos, const float* __restrict__ pm,
    const float* __restrict__ eW1,
    const float* __restrict__ eW2, const float* __restrict__ eb2,
    const float* __restrict__ sW1, const float* __restrict__ sb1,
    const float* __restrict__ sW2, const float* __restrict__ sb2,
    const float* __restrict__ vW2g, const float* __restrict__ vb2g,
    const float* __restrict__ lnw, const float* __restrict__ lnb,
    const float* __restrict__ Ag, const float* __restrict__ Bvg,
    const unsigned short* __restrict__ E2V1Tg, const float* __restrict__ m2g,
    const float* __restrict__ c1g, const float* __restrict__ mbg,
    float* __restrict__ sout, float* __restrict__ vout, float* __restrict__ ewout)
{
  __shared__ __align__(16) unsigned short eTs[128*128];   // 32 KB, [col][k^((col&7)<<3)]
  __shared__ __align__(16) float BvL[DD], w256L[DD], w259L[DD], m2L[DD];
  __shared__ __align__(16) float c1L[DD], vw2L[DD];
  __shared__ float redS[4], redVx[4], redVy[4], redVz[4], redA[2], redB[2];

  const int tid = threadIdx.x;
  const int ni  = blockIdx.x;
  const int nb  = ni & ~(NN - 1);

  const int l   = tid & 63, w = tid >> 6;
  const int l15 = l & 15,  lg = l >> 4;
  const int d   = tid & 127, sub = tid >> 7;
  const int d0base = lg*8;

  // stage E2V1 (pre-swizzled bf16) into LDS
  {
    const uint4* src = (const uint4*)E2V1Tg;
    uint4* dst = (uint4*)eTs;
    #pragma unroll
    for (int it = 0; it < 8; ++it) dst[tid + it*256] = src[tid + it*256];
  }
  if (tid < 128) {
    BvL[tid]   = Bvg[(size_t)ni*DD + tid];
    w256L[tid] = eW1[256*DD + tid];
    w259L[tid] = eW1[259*DD + tid];
    m2L[tid]   = m2g[tid];
    c1L[tid]   = c1g[tid];
    vw2L[tid]  = vW2g[tid];
  }
  const float pix = pos[ni*3+0], piy = pos[ni*3+1], piz = pos[ni*3+2];
  const float mbv = mbg[0], vb2v = vb2g[0];

  float Sreg[4][8];
  #pragma unroll
  for (int kk = 0; kk < 4; ++kk)
    #pragma unroll
    for (int m = 0; m < 8; ++m) Sreg[kk][m] = 0.f;
  float vmx = 0.f, vmy = 0.f, vmz = 0.f, swacc = 0.f;

  __syncthreads();

  for (int t = 0; t < 8; ++t) {
    const int row = t*64 + w*16 + l15;     // this lane's A-row
    float px = pos[(nb + row)*3 + 0];
    float py = pos[(nb + row)*3 + 1];
    float pz = pos[(nb + row)*3 + 2];
    float rx = pix - px, ry = piy - py, rz = piz - pz;
    float dist = fmaxf(sqrtf(rx*rx + ry*ry + rz*rz), 1e-8f);
    float inv = __builtin_amdgcn_rcpf(dist);
    float dirx = rx*inv, diry = ry*inv, dirz = rz*inv;
    float mj = pm[(size_t)ni*NN + row];

    // ---- A: h in MFMA A-frag layout -> named uint4 packs (SROA-safe) ----
    uint4 pk0, pk1, pk2, pk3;
    float dot = 0.f;
    const float* agrow = Ag + (size_t)(nb + row)*DD;

#define A_STEP(KK, PK) {                                                        \
    const int d0 = (KK)*32 + d0base;                                            \
    float4 a0 = *(const float4*)(agrow + d0), a1 = *(const float4*)(agrow + d0 + 4); \
    float4 b0 = *(const float4*)&BvL[d0],   b1 = *(const float4*)&BvL[d0+4];    \
    float4 wa0= *(const float4*)&w256L[d0], wa1= *(const float4*)&w256L[d0+4];  \
    float4 wb0= *(const float4*)&w259L[d0], wb1= *(const float4*)&w259L[d0+4];  \
    float4 m20= *(const float4*)&m2L[d0],   m21= *(const float4*)&m2L[d0+4];    \
    float h0 = siluf_(b0.x + a0.x + dist*wa0.x + mj*wb0.x);                     \
    float h1 = siluf_(b0.y + a0.y + dist*wa0.y + mj*wb0.y);                     \
    float h2 = siluf_(b0.z + a0.z + dist*wa0.z + mj*wb0.z);                     \
    float h3 = siluf_(b0.w + a0.w + dist*wa0.w + mj*wb0.w);                     \
    float h4 = siluf_(b1.x + a1.x + dist*wa1.x + mj*wb1.x);                     \
    float h5 = siluf_(b1.y + a1.y + dist*wa1.y + mj*wb1.y);                     \
    float h6 = siluf_(b1.z + a1.z + dist*wa1.z + mj*wb1.z);                     \
    float h7 = siluf_(b1.w + a1.w + dist*wa1.w + mj*wb1.w);                     \
    PK.x = cvtpk_(h0, h1); PK.y = cvtpk_(h2, h3);                               \
    PK.z = cvtpk_(h4, h5); PK.w = cvtpk_(h6, h7);                               \
    dot += h0*m20.x + h1*m20.y + h2*m20.z + h3*m20.w                            \
         + h4*m21.x + h5*m21.y + h6*m21.z + h7*m21.w; }

    A_STEP(0, pk0)
    A_STEP(1, pk1)
    A_STEP(2, pk2)
    A_STEP(3, pk3)
#undef A_STEP

    dot += __shfl_xor(dot, 16);
    dot += __shfl_xor(dot, 32);
    const float w_full = mj * sigmoidf_(dot + mbv);
    if (lg == 0) {
      ewout[(size_t)ni*NN + row] = w_full;
      swacc += w_full;
    }

#define S_STEP(KK, PK) {                                          \
    Sreg[KK][0] = fmaf(w_full, bflo_(PK.x), Sreg[KK][0]);         \
    Sreg[KK][1] = fmaf(w_full, bfhi_(PK.x), Sreg[KK][1]);         \
    Sreg[KK][2] = fmaf(w_full, bflo_(PK.y), Sreg[KK][2]);         \
    Sreg[KK][3] = fmaf(w_full, bfhi_(PK.y), Sreg[KK][3]);         \
    Sreg[KK][4] = fmaf(w_full, bflo_(PK.z), Sreg[KK][4]);         \
    Sreg[KK][5] = fmaf(w_full, bfhi_(PK.z), Sreg[KK][5]);         \
    Sreg[KK][6] = fmaf(w_full, bflo_(PK.w), Sreg[KK][6]);         \
    Sreg[KK][7] = fmaf(w_full, bfhi_(PK.w), Sreg[KK][7]); }

    S_STEP(0, pk0)
    S_STEP(1, pk1)
    S_STEP(2, pk2)
    S_STEP(3, pk3)
#undef S_STEP

    const bf16x8 af0 = __builtin_bit_cast(bf16x8, pk0);
    const bf16x8 af1 = __builtin_bit_cast(bf16x8, pk1);
    const bf16x8 af2 = __builtin_bit_cast(bf16x8, pk2);
    const bf16x8 af3 = __builtin_bit_cast(bf16x8, pk3);

    // ---- B: wave-local MFMA over all 128 cols; gate reduce in-wave ----
    float gp[4] = {0.f, 0.f, 0.f, 0.f};
    #pragma unroll
    for (int ct = 0; ct < 8; ++ct) {
      const int col = ct*16 + l15;
      const int swz = (col & 7) << 3;
      const unsigned short* ecol = &eTs[col*DD];
      bf16x8 bf0 = *(const bf16x8*)&ecol[(  0 + d0base) ^ swz];
      bf16x8 bf1 = *(const bf16x8*)&ecol[( 32 + d0base) ^ swz];
      bf16x8 bf2 = *(const bf16x8*)&ecol[( 64 + d0base) ^ swz];
      bf16x8 bf3 = *(const bf16x8*)&ecol[( 96 + d0base) ^ swz];
      f32x4 c = {0.f, 0.f, 0.f, 0.f};
      c = __builtin_amdgcn_mfma_f32_16x16x32_bf16(af0, bf0, c, 0, 0, 0);
      c = __builtin_amdgcn_mfma_f32_16x16x32_bf16(af1, bf1, c, 0, 0, 0);
      c = __builtin_amdgcn_mfma_f32_16x16x32_bf16(af2, bf2, c, 0, 0, 0);
      c = __builtin_amdgcn_mfma_f32_16x16x32_bf16(af3, bf3, c, 0, 0, 0);
      const float c1c = c1L[col], vw2c = vw2L[col];
      gp[0] += siluf_(c[0] + c1c) * vw2c;
      gp[1] += siluf_(c[1] + c1c) * vw2c;
      gp[2] += siluf_(c[2] + c1c) * vw2c;
      gp[3] += siluf_(c[3] + c1c) * vw2c;
    }
    #pragma unroll
    for (int r = 0; r < 4; ++r) {
      float v = gp[r];
      v += __shfl_xor(v, 1);
      v += __shfl_xor(v, 2);
      v += __shfl_xor(v, 4);
      v += __shfl_xor(v, 8);
      const int srow = lg*4 + r;            // C row within the 16-block
      float wrow = __shfl(w_full, srow);
      float g = (v + vb2v) * wrow;
      float dx = __shfl(dirx, srow);
      float dy = __shfl(diry, srow);
      float dz = __shfl(dirz, srow);
      if (l15 == 0) {
        vmx = fmaf(g, dx, vmx);
        vmy = fmaf(g, dy, vmy);
        vmz = fmaf(g, dz, vmz);
      }
    }
  }

  // -------- epilogue --------
  __syncthreads();                 // all eTs reads done before aliasing
  float* scr   = (float*)eTs;
  float* Spart = scr;              // [4][128]
  float* SL    = scr + 512;
  float* partA = scr + 640;
  float* msgL  = scr + 768;
  float* u1L   = scr + 896;
  float* xoL   = scr + 1024;

  #pragma unroll
  for (int kk = 0; kk < 4; ++kk)
    #pragma unroll
    for (int m = 0; m < 8; ++m) {
      float v = Sreg[kk][m];
      v += __shfl_xor(v, 1);
      v += __shfl_xor(v, 2);
      v += __shfl_xor(v, 4);
      v += __shfl_xor(v, 8);
      Sreg[kk][m] = v;
    }
  if (l15 == 0) {
    #pragma unroll
    for (int kk = 0; kk < 4; ++kk)
      #pragma unroll
      for (int m = 0; m < 8; ++m)
        Spart[w*128 + kk*32 + lg*8 + m] = Sreg[kk][m];
  }
  {
    float sw = swacc;
    #pragma unroll
    for (int off = 1; off < 64; off <<= 1) sw += __shfl_xor(sw, off);
    if (l == 0) redS[w] = sw;
  }
  {
    float vx = vmx, vy = vmy, vz = vmz;
    #pragma unroll
    for (int off = 1; off < 64; off <<= 1) {
      vx += __shfl_xor(vx, off);
      vy += __shfl_xor(vy, off);
      vz += __shfl_xor(vz, off);
    }
    if (l == 0) { redVx[w] = vx; redVy[w] = vy; redVz[w] = vz; }
  }
  __syncthreads();
  if (tid < 128) SL[tid] = Spart[tid] + Spart[128+tid] + Spart[256+tid] + Spart[384+tid];
  if (tid == 0) {
    vout[ni*3 + 0] = vf[ni*3 + 0] + redVx[0]+redVx[1]+redVx[2]+redVx[3];
    vout[ni*3 + 1] = vf[ni*3 + 1] + redVy[0]+redVy[1]+redVy[2]+redVy[3];
    vout[ni*3 + 2] = vf[ni*3 + 2] + redVz[0]+redVz[1]+redVz[2]+redVz[3];
  }
  __syncthreads();
  const float sumwv = redS[0] + redS[1] + redS[2] + redS[3];

  // message_scalar = S@eW2 + sumw*eb2
  float p = 0.f;
  { int k0 = sub*64;
    #pragma unroll 4
    for (int k = k0; k < k0 + 64; ++k) p = fmaf(SL[k], eW2[k*DD + d], p); }
  if (sub) partA[d] = p;
  __syncthreads();
  if (!sub) msgL[d] = p + partA[d] + sumwv * eb2[d];
  __syncthreads();

  // u1 = silu([x, msg] @ sW1 + sb1)
  float q = 0.f;
  if (!sub) {
    const float* xr = sf + (size_t)ni*DD;
    #pragma unroll 4
    for (int tt = 0; tt < 128; ++tt) q = fmaf(xr[tt], sW1[tt*DD + d], q);
  } else {
    #pragma unroll 4
    for (int tt = 0; tt < 128; ++tt) q = fmaf(msgL[tt], sW1[(128 + tt)*DD + d], q);
  }
  if (sub) partA[d] = q;
  __syncthreads();
  if (!sub) u1L[d] = siluf_(q + partA[d] + sb1[d]);
  __syncthreads();

  // upd = u1 @ sW2 + sb2; x = sf + upd
  float r2 = 0.f;
  { int t0 = sub*64;
    #pragma unroll 4
    for (int tt = t0; tt < t0 + 64; ++tt) r2 = fmaf(u1L[tt], sW2[tt*DD + d], r2); }
  if (sub) partA[d] = r2;
  __syncthreads();
  if (!sub) xoL[d] = sf[(size_t)ni*DD + d] + r2 + partA[d] + sb2[d];
  __syncthreads();

  // LayerNorm
  if (tid < 128) {
    float v = xoL[tid];
    float s1 = v, s2 = v*v;
    #pragma unroll
    for (int off = 1; off < 64; off <<= 1) { s1 += __shfl_xor(s1, off); s2 += __shfl_xor(s2, off); }
    if ((tid & 63) == 0) { redA[tid >> 6] = s1; redB[tid >> 6] = s2; }
  }
  __syncthreads();
  if (tid < 128) {
    float s1 = redA[0] + redA[1], s2 = redB[0] + redB[1];
    float mu = s1 * 0.0078125f;
    float var = s2 * 0.0078125f - mu*mu;
    sout[(size_t)ni*DD + tid] = (xoL[tid] - mu) * rsqrtf(var + 1e-5f) * lnw[tid] + lnb[tid];
  }
}

extern "C" void kernel_launch(void* const* d_in, const int* in_sizes, int n_in,
                              void* d_out, int out_size, void* d_ws, size_t ws_size,
                              hipStream_t stream) {
  const float* sf   = (const float*)d_in[0];
  const float* vf   = (const float*)d_in[1];
  const float* pos  = (const float*)d_in[2];
  const float* pm   = (const float*)d_in[3];
  const float* cons = (const float*)d_in[4];
  const float* eW1  = (const float*)d_in[5];
  const float* eb1  = (const float*)d_in[6];
  const float* eW2  = (const float*)d_in[7];
  const float* eb2  = (const float*)d_in[8];
  const float* sW1  = (const float*)d_in[9];
  const float* sb1  = (const float*)d_in[10];
  const float* sW2  = (const float*)d_in[11];
  const float* sb2  = (const float*)d_in[12];
  const float* vW1  = (const float*)d_in[13];
  const float* vb1  = (const float*)d_in[14];
  const float* vW2  = (const float*)d_in[15];
  const float* vb2  = (const float*)d_in[16];
  const float* lnw  = (const float*)d_in[17];
  const float* lnb  = (const float*)d_in[18];

  float* ws   = (float*)d_ws;
  float* Ag   = ws;                              // 1024*128 f32
  float* Bvg  = ws + 131072;                     // 1024*128 f32
  float* m2   = ws + 262144;                     // 128
  float* c1   = ws + 262272;                     // 128
  float* mb   = ws + 262400;                     // 1 (+pad)
  unsigned short* E2V1T = (unsigned short*)(ws + 262404); // 128*128 bf16, 16B-aligned

  float* sout  = (float*)d_out;      // [2,512,128]
  float* vout  = sout + 131072;      // [2,512,3]
  float* ewout = sout + 134144;      // [2,512,512]

  hipLaunchKernelGGL(prep_kernel, dim3(NODES + 129), dim3(128), 0, stream,
                     sf, cons, eW1, eb1, eW2, eb2, vW1, vb1,
                     Ag, Bvg, E2V1T, m2, c1, mb);
  hipLaunchKernelGGL(edge_kernel, dim3(NODES), dim3(256), 0, stream,
                     sf, vf, pos, pm, eW1, eW2, eb2, sW1, sb1, sW2, sb2,
                     vW2, vb2, lnw, lnb, Ag, Bvg, E2V1T, m2, c1, mb,
                     sout, vout, ewout);
}